// Round 2
// baseline (478.928 us; speedup 1.0000x reference)
//
#include <hip/hip_runtime.h>
#include <math.h>

#define B_SZ    16384
#define NNZ_PER 32
#define NNZ     (B_SZ * NNZ_PER)
#define FT_OUT  512
#define F_BIG   49152
#define F_SMALL 768
#define MODV    640

// prep grid partition
#define TP_A     1536              // W_ft tiles: 768 c-tiles(64) x 2 o-tiles(256)
#define TP_B     80                // W_fft 64x64 tiles: 8 ot x 10 ct
#define HISTB    (2 * MODV)        // 1280: one block per (side, histogram row r)
#define PREP_GRID (TP_A + TP_B + HISTB)

#define FFT_ROWS   32                              // s-rows per fft_gemm block
#define FFT_BLOCKS (2 * MODV / FFT_ROWS)           // 40

// ---------------------------------------------------------------------------
// ws layout:
//   Wt_bf   : F_BIG*FT_OUT ushort      48 MB  transposed big weight, bf16
//   Wfft_t  : MODV*FT_OUT float        1.3 MB transposed small weight (fp32)
//   H       : 2*MODV*MODV float        3.3 MB weighted histograms
//   fft_acc : 2*MODV*FT_OUT float      2.6 MB H @ Wfft^T per side
// ---------------------------------------------------------------------------

__device__ __forceinline__ unsigned short f32_to_bf16_rne(float f) {
    union { float f; unsigned int u; } v; v.f = f;
    unsigned int u = v.u;
    return (unsigned short)((u + 0x7fffu + ((u >> 16) & 1u)) >> 16);
}

__device__ __forceinline__ void unpack_bf16x2(unsigned int u, float& lo, float& hi) {
    union { unsigned int i; float f; } a, b;
    a.i = u << 16;            // even element
    b.i = u & 0xffff0000u;    // odd element
    lo = a.f; hi = b.f;
}

__device__ __forceinline__ float clip01(float x) {
    return fminf(fmaxf(x, 0.0f), 1.0f);
}

// Fused prologue: transpose+bf16-quantize W_ft, transpose W_fft, histogram.
// All stores CACHED (not nontemporal): Wt/Wfft_t are re-read by later kernels,
// NT in R6 evicted them from L3 and cost main ~5% (R2 vs R6 evidence).
//
// Histogram rewrite (R2): COO rows are repeat(arange(B),32), so the histogram
// row r = (j/32) % 640 is index-determined. One block per (side, r) owns all
// ~26*32 contributing nnz: build the 640-float row in LDS (LDS atomics only),
// store coalesced. Replaces ~1M random global atomicAdds (suspected ~120 us
// at few-GOPS atomic throughput) with ~15 MB of coalesced traffic; also kills
// the H memset dispatch (every row fully written).
__global__ __launch_bounds__(256)
void prep_kernel(const float* __restrict__ W_ft, const float* __restrict__ W_fft,
                 const int* __restrict__ stm, const int* __restrict__ nstm,
                 const float* __restrict__ vals,
                 unsigned short* __restrict__ Wt, float* __restrict__ Wfft_t,
                 float* __restrict__ H) {
    __shared__ __align__(16) unsigned char smem[256 * 68 * 2];   // 34.8 KB
    int b = blockIdx.x;
    int tid = threadIdx.x;
    if (b < TP_A) {
        // ---- W_ft transpose: tile c0..c0+63, o0..o0+255; LDS bf16 tA[o][c] ----
        unsigned short (*tA)[68] = (unsigned short (*)[68])smem;
        int ct = b >> 1, ot = b & 1;
        int c0 = ct * 64, o0 = ot * 256;
        int orow = tid >> 4, c4 = (tid & 15) * 4;
#pragma unroll
        for (int it = 0; it < 16; it++) {
            int oo = orow + it * 16;
            float4 f = *(const float4*)(W_ft + (size_t)(o0 + oo) * F_BIG + c0 + c4);
            tA[oo][c4 + 0] = f32_to_bf16_rne(f.x);
            tA[oo][c4 + 1] = f32_to_bf16_rne(f.y);
            tA[oo][c4 + 2] = f32_to_bf16_rne(f.z);
            tA[oo][c4 + 3] = f32_to_bf16_rne(f.w);
        }
        __syncthreads();
        // store v2: lane = column cc (stride-1 u16 LDS reads, conflict-free);
        // each lane emits 128 B contiguous (64 o) of its Wt row.
        int cc = tid & 63, och = tid >> 6;      // och 0..3
        int obase = och * 64;
        unsigned short* dst = Wt + (size_t)(c0 + cc) * FT_OUT + o0 + obase;
#pragma unroll
        for (int k = 0; k < 8; k++) {
            int o8 = obase + k * 8;
            uint4 pk;
            pk.x = (unsigned int)tA[o8 + 0][cc] | ((unsigned int)tA[o8 + 1][cc] << 16);
            pk.y = (unsigned int)tA[o8 + 2][cc] | ((unsigned int)tA[o8 + 3][cc] << 16);
            pk.z = (unsigned int)tA[o8 + 4][cc] | ((unsigned int)tA[o8 + 5][cc] << 16);
            pk.w = (unsigned int)tA[o8 + 6][cc] | ((unsigned int)tA[o8 + 7][cc] << 16);
            *(uint4*)(dst + k * 8) = pk;
        }
    } else if (b < TP_A + TP_B) {
        // ---- W_fft transpose: 64x64 fp32 tiles ----
        float (*tB)[65] = (float (*)[65])smem;
        int b2 = b - TP_A;
        int nct = MODV / 64;
        int ot = b2 / nct, ct = b2 % nct;
        int c0 = ct * 64, o0 = ot * 64;
        int rr = tid >> 4, c4 = (tid & 15) * 4;
#pragma unroll
        for (int it = 0; it < 4; it++) {
            int oo = rr + it * 16;
            float4 f = *(const float4*)(W_fft + (size_t)(o0 + oo) * F_SMALL + c0 + c4);
            tB[oo][c4 + 0] = f.x; tB[oo][c4 + 1] = f.y;
            tB[oo][c4 + 2] = f.z; tB[oo][c4 + 3] = f.w;
        }
        __syncthreads();
#pragma unroll
        for (int it = 0; it < 4; it++) {
            int idx = tid + it * 256;
            int cc = idx >> 4, g = idx & 15;
            float4 v = make_float4(tB[g * 4 + 0][cc], tB[g * 4 + 1][cc],
                                   tB[g * 4 + 2][cc], tB[g * 4 + 3][cc]);
            *(float4*)(Wfft_t + (size_t)(c0 + cc) * FT_OUT + o0 + g * 4) = v;
        }
    } else {
        // ---- mod-640 weighted histogram, LDS-private per (side, r) ----
        float* hrow = (float*)smem;                  // 640 floats
        int hb   = b - TP_A - TP_B;                  // 0..1279
        int side = (hb >= MODV) ? 1 : 0;
        int r    = hb - side * MODV;
        const int* cols = (side ? nstm : stm) + NNZ; // col indices at offset NNZ
        for (int i = tid; i < MODV; i += 256) hrow[i] = 0.0f;
        __syncthreads();
        int nb  = (B_SZ - r + MODV - 1) / MODV;      // batch rows with row%640==r
        int tot = nb * NNZ_PER;
        for (int idx = tid; idx < tot; idx += 256) {
            // j = (r + (idx>>5)*MODV) * 32 + (idx&31)
            int j = r * NNZ_PER + (idx >> 5) * (MODV * NNZ_PER) + (idx & 31);
            int c = cols[j] % MODV;
            atomicAdd(&hrow[c], vals[j]);
        }
        __syncthreads();
        float* dst = H + ((size_t)side * MODV + r) * MODV;
        for (int i = tid; i < MODV; i += 256) dst[i] = hrow[i];
    }
}

// acc[side][s][o] = sum_cc H[side][s][cc] * Wfft_t[cc][o]
// 32 s-rows per block -> 40 blocks: Wfft_t re-read = 40 x 1.3 MB = 52 MB
// (was 320 x 1.3 MB = 416 MB ~= 50 us in R0; predict ~17 us now)
__global__ __launch_bounds__(512)
void fft_gemm(const float* __restrict__ H, const float* __restrict__ Wfft_t,
              float* __restrict__ acc) {
    __shared__ float hs[FFT_ROWS][MODV];             // 80 KB -> 1 block/CU
    int o = threadIdx.x;                             // 0..511
    int b = blockIdx.x;
    int side = b / (MODV / FFT_ROWS);
    int s0   = (b % (MODV / FFT_ROWS)) * FFT_ROWS;
    const float* Hs = H + (size_t)side * MODV * MODV + (size_t)s0 * MODV;
    for (int t = threadIdx.x; t < FFT_ROWS * MODV; t += 512)
        ((float*)hs)[t] = Hs[t];
    __syncthreads();
    float a[FFT_ROWS];
#pragma unroll
    for (int j = 0; j < FFT_ROWS; j++) a[j] = 0.0f;
#pragma unroll 2
    for (int cc = 0; cc < MODV; cc++) {
        float wv = Wfft_t[(size_t)cc * FT_OUT + o];
#pragma unroll
        for (int j = 0; j < FFT_ROWS; j++) a[j] += hs[j][cc] * wv;
    }
    float* dst = acc + ((size_t)side * MODV + s0) * FT_OUT + o;
#pragma unroll
    for (int j = 0; j < FFT_ROWS; j++) dst[(size_t)j * FT_OUT] = a[j];
}

// one block (= one wave, 64 threads) per row — empirically fastest config.
// R1 lesson: gather BW saturates ~3.0-3.6 TB/s regardless of occupancy
// (10.7% vs 67% -> only -17% BW), so this low-VGPR (36) high-occupancy shape
// is at the random-1KB-gather pattern ceiling; do not re-tune.
__global__ __launch_bounds__(64)
void main_kernel(const int* __restrict__ stm, const int* __restrict__ nstm,
                 const float* __restrict__ vals,
                 const unsigned short* __restrict__ Wt,
                 const float* __restrict__ b_ft, const float* __restrict__ b_fft,
                 const float* __restrict__ fft_acc,
                 const float* __restrict__ W_out, const float* __restrict__ b_out,
                 float* __restrict__ out) {
    int row = blockIdx.x;
    int tid = threadIdx.x;   // 0..63

    __shared__ int   s_c[2][NNZ_PER];
    __shared__ float s_v[NNZ_PER];
    if (tid < NNZ_PER) {
        s_c[0][tid] = stm[NNZ + row * NNZ_PER + tid];
        s_v[tid]    = vals[row * NNZ_PER + tid];
    } else {
        int k = tid - NNZ_PER;
        s_c[1][k] = nstm[NNZ + row * NNZ_PER + k];
    }
    __syncthreads();

    float a0[8] = {0, 0, 0, 0, 0, 0, 0, 0};   // stm, features tid*8..tid*8+7
    float a1[8] = {0, 0, 0, 0, 0, 0, 0, 0};   // nstm

#pragma unroll 8
    for (int k = 0; k < NNZ_PER; k++) {
        float v = s_v[k];
        const uint4* p0 = (const uint4*)(Wt + (size_t)s_c[0][k] * FT_OUT);
        const uint4* p1 = (const uint4*)(Wt + (size_t)s_c[1][k] * FT_OUT);
        uint4 w0 = p0[tid];
        uint4 w1 = p1[tid];
        float e0, e1;
        unpack_bf16x2(w0.x, e0, e1); a0[0] += v * e0; a0[1] += v * e1;
        unpack_bf16x2(w0.y, e0, e1); a0[2] += v * e0; a0[3] += v * e1;
        unpack_bf16x2(w0.z, e0, e1); a0[4] += v * e0; a0[5] += v * e1;
        unpack_bf16x2(w0.w, e0, e1); a0[6] += v * e0; a0[7] += v * e1;
        unpack_bf16x2(w1.x, e0, e1); a1[0] += v * e0; a1[1] += v * e1;
        unpack_bf16x2(w1.y, e0, e1); a1[2] += v * e0; a1[3] += v * e1;
        unpack_bf16x2(w1.z, e0, e1); a1[4] += v * e0; a1[5] += v * e1;
        unpack_bf16x2(w1.w, e0, e1); a1[6] += v * e0; a1[7] += v * e1;
    }

    int ob = tid * 8;
    float bft[8], bff[8], wo0[8], wo1[8], fa0[8], fa1[8];
    *(float4*)&bft[0] = ((const float4*)(b_ft + ob))[0];
    *(float4*)&bft[4] = ((const float4*)(b_ft + ob))[1];
    *(float4*)&bff[0] = ((const float4*)(b_fft + ob))[0];
    *(float4*)&bff[4] = ((const float4*)(b_fft + ob))[1];
    *(float4*)&wo0[0] = ((const float4*)(W_out + ob))[0];
    *(float4*)&wo0[4] = ((const float4*)(W_out + ob))[1];
    *(float4*)&wo1[0] = ((const float4*)(W_out + FT_OUT + ob))[0];
    *(float4*)&wo1[4] = ((const float4*)(W_out + FT_OUT + ob))[1];
#pragma unroll
    for (int i = 0; i < 8; i++) { fa0[i] = 0.0f; fa1[i] = 0.0f; }
    if (row < MODV) {
        const float* p0 = fft_acc + (size_t)row * FT_OUT + ob;
        const float* p1 = fft_acc + (size_t)(MODV + row) * FT_OUT + ob;
        *(float4*)&fa0[0] = ((const float4*)p0)[0];
        *(float4*)&fa0[4] = ((const float4*)p0)[1];
        *(float4*)&fa1[0] = ((const float4*)p1)[0];
        *(float4*)&fa1[4] = ((const float4*)p1)[1];
    }

    float dot = 0.0f;
#pragma unroll
    for (int i = 0; i < 8; i++) {
        float h0 = clip01(a0[i] + bft[i] + bff[i] + fa0[i]);
        float h1 = clip01(a1[i] + bft[i] + bff[i] + fa1[i]);
        dot += h0 * wo0[i] + h1 * wo1[i];
    }

#pragma unroll
    for (int off = 32; off > 0; off >>= 1)
        dot += __shfl_down(dot, off, 64);

    if (tid == 0)
        out[row] = 1.0f / (1.0f + expf(-(dot + b_out[0])));
}

extern "C" void kernel_launch(void* const* d_in, const int* in_sizes, int n_in,
                              void* d_out, int out_size, void* d_ws, size_t ws_size,
                              hipStream_t stream) {
    const int*   stm   = (const int*)d_in[0];
    const int*   nstm  = (const int*)d_in[1];
    const float* vals  = (const float*)d_in[2];
    // d_in[3]: size scalar (compile-time B_SZ)
    const float* W_ft  = (const float*)d_in[4];
    const float* b_ft  = (const float*)d_in[5];
    const float* W_fft = (const float*)d_in[6];
    const float* b_fft = (const float*)d_in[7];
    const float* W_out = (const float*)d_in[8];
    const float* b_out = (const float*)d_in[9];
    float* out = (float*)d_out;

    unsigned short* Wt_bf = (unsigned short*)d_ws;                  // F_BIG*FT_OUT ushort
    float* Wfft_t  = (float*)(Wt_bf + (size_t)F_BIG * FT_OUT);      // MODV*FT_OUT
    float* H       = Wfft_t + (size_t)MODV * FT_OUT;                // 2*MODV*MODV
    float* fft_acc = H + (size_t)2 * MODV * MODV;                   // 2*MODV*FT_OUT

    // no H memset needed: every (side, r) histogram row is fully written by
    // its ownership block in prep_kernel.

    prep_kernel<<<PREP_GRID, 256, 0, stream>>>(W_ft, W_fft, stm, nstm, vals,
                                               Wt_bf, Wfft_t, H);
    fft_gemm<<<FFT_BLOCKS, 512, 0, stream>>>(H, Wfft_t, fft_acc);
    main_kernel<<<B_SZ, 64, 0, stream>>>(stm, nstm, vals, Wt_bf, b_ft, b_fft,
                                         fft_acc, W_out, b_out, out);
}

// Round 3
// 308.072 us; speedup vs baseline: 1.5546x; 1.5546x over previous
//
#include <hip/hip_runtime.h>
#include <math.h>

#define B_SZ    16384
#define NNZ_PER 32
#define NNZ     (B_SZ * NNZ_PER)
#define FT_OUT  512
#define F_BIG   49152
#define F_SMALL 768
#define MODV    640

// prep_big grid
#define TP_A     1536              // W_ft tiles: 768 c-tiles(64) x 2 o-tiles(256)
// prep_small grid partition
#define TP_B     80                // W_fft 64x64 tiles: 8 ot x 10 ct
#define HISTB    (2 * MODV)        // 1280: one block per (side, histogram row r)
#define PREPS_GRID (TP_B + HISTB)

// main slicing: 16 slices x 32 features, slice-major Wt layout [s][col][32]
#define NSLICE  16
#define SL_F    32
#define MAIN_GRID (NSLICE * (B_SZ / 4))   // 65536 blocks, 4 rows each

// ---------------------------------------------------------------------------
// ws layout:
//   Wt_bf   : F_BIG*FT_OUT ushort      48 MB  slice-major bf16 weight
//   Wfft_t  : MODV*FT_OUT float        1.3 MB transposed small weight (fp32)
//   H       : 2*MODV*MODV float        3.3 MB weighted histograms
//   fft_acc : 2*MODV*FT_OUT float      2.6 MB H @ Wfft^T per side
//   partial : NSLICE*B_SZ float        1.0 MB per-slice partial dots
// ---------------------------------------------------------------------------

__device__ __forceinline__ unsigned short f32_to_bf16_rne(float f) {
    union { float f; unsigned int u; } v; v.f = f;
    unsigned int u = v.u;
    return (unsigned short)((u + 0x7fffu + ((u >> 16) & 1u)) >> 16);
}

__device__ __forceinline__ void unpack_bf16x2(unsigned int u, float& lo, float& hi) {
    union { unsigned int i; float f; } a, b;
    a.i = u << 16;            // even element
    b.i = u & 0xffff0000u;    // odd element
    lo = a.f; hi = b.f;
}

__device__ __forceinline__ float clip01(float x) {
    return fminf(fmaxf(x, 0.0f), 1.0f);
}

// ---- W_ft transpose+quantize into slice-major layout ----------------------
// dst[s][col][f] with s = o/32, f = o%32: main's slice s is a contiguous 3 MB
// region -> fits one XCD's 4 MB L2 with full cache-line utilization.
__global__ __launch_bounds__(256)
void prep_big(const float* __restrict__ W_ft, unsigned short* __restrict__ Wt) {
    __shared__ __align__(16) unsigned short tA[256][68];   // 34.8 KB
    int b = blockIdx.x;
    int tid = threadIdx.x;
    int ct = b >> 1, ot = b & 1;
    int c0 = ct * 64, o0 = ot * 256;
    int orow = tid >> 4, c4 = (tid & 15) * 4;
#pragma unroll
    for (int it = 0; it < 16; it++) {
        int oo = orow + it * 16;
        float4 f = *(const float4*)(W_ft + (size_t)(o0 + oo) * F_BIG + c0 + c4);
        tA[oo][c4 + 0] = f32_to_bf16_rne(f.x);
        tA[oo][c4 + 1] = f32_to_bf16_rne(f.y);
        tA[oo][c4 + 2] = f32_to_bf16_rne(f.z);
        tA[oo][c4 + 3] = f32_to_bf16_rne(f.w);
    }
    __syncthreads();
    // lane cc owns column c0+cc; och selects 64-o chunk; k walks 8-o groups.
    // global o = o0 + och*64 + k*8 + j  ->  slice s = o/32, in-slice f = o%32
    int cc = tid & 63, och = tid >> 6;      // och 0..3
    int obase = och * 64;
#pragma unroll
    for (int k = 0; k < 8; k++) {
        int o8 = obase + k * 8;
        uint4 pk;
        pk.x = (unsigned int)tA[o8 + 0][cc] | ((unsigned int)tA[o8 + 1][cc] << 16);
        pk.y = (unsigned int)tA[o8 + 2][cc] | ((unsigned int)tA[o8 + 3][cc] << 16);
        pk.z = (unsigned int)tA[o8 + 4][cc] | ((unsigned int)tA[o8 + 5][cc] << 16);
        pk.w = (unsigned int)tA[o8 + 6][cc] | ((unsigned int)tA[o8 + 7][cc] << 16);
        int og = o0 + o8;                    // global o of first elem (mult of 8)
        int s  = og >> 5;                    // slice
        int f  = og & 31;                    // offset within slice (0,8,16,24)
        *(uint4*)(Wt + ((size_t)s * F_BIG + (c0 + cc)) * SL_F + f) = pk;
    }
}

// ---- W_fft transpose + LDS-private histogram ------------------------------
__global__ __launch_bounds__(256)
void prep_small(const float* __restrict__ W_fft,
                const int* __restrict__ stm, const int* __restrict__ nstm,
                const float* __restrict__ vals,
                float* __restrict__ Wfft_t, float* __restrict__ H) {
    __shared__ __align__(16) float smem[64 * 65];          // 16.6 KB
    int b = blockIdx.x;
    int tid = threadIdx.x;
    if (b < TP_B) {
        float (*tB)[65] = (float (*)[65])smem;
        int nct = MODV / 64;
        int ot = b / nct, ct = b % nct;
        int c0 = ct * 64, o0 = ot * 64;
        int rr = tid >> 4, c4 = (tid & 15) * 4;
#pragma unroll
        for (int it = 0; it < 4; it++) {
            int oo = rr + it * 16;
            float4 f = *(const float4*)(W_fft + (size_t)(o0 + oo) * F_SMALL + c0 + c4);
            tB[oo][c4 + 0] = f.x; tB[oo][c4 + 1] = f.y;
            tB[oo][c4 + 2] = f.z; tB[oo][c4 + 3] = f.w;
        }
        __syncthreads();
#pragma unroll
        for (int it = 0; it < 4; it++) {
            int idx = tid + it * 256;
            int cc = idx >> 4, g = idx & 15;
            float4 v = make_float4(tB[g * 4 + 0][cc], tB[g * 4 + 1][cc],
                                   tB[g * 4 + 2][cc], tB[g * 4 + 3][cc]);
            *(float4*)(Wfft_t + (size_t)(c0 + cc) * FT_OUT + o0 + g * 4) = v;
        }
    } else {
        // one block per (side, r): build 640-float histogram row in LDS.
        // COO rows are repeat(arange(B),32) so r = (j/32) % 640 is index-known.
        float* hrow = smem;
        int hb   = b - TP_B;                         // 0..1279
        int side = (hb >= MODV) ? 1 : 0;
        int r    = hb - side * MODV;
        const int* cols = (side ? nstm : stm) + NNZ; // col indices at offset NNZ
        for (int i = tid; i < MODV; i += 256) hrow[i] = 0.0f;
        __syncthreads();
        int nb  = (B_SZ - r + MODV - 1) / MODV;      // batch rows with row%640==r
        int tot = nb * NNZ_PER;
        for (int idx = tid; idx < tot; idx += 256) {
            int j = r * NNZ_PER + (idx >> 5) * (MODV * NNZ_PER) + (idx & 31);
            int c = cols[j] % MODV;
            atomicAdd(&hrow[c], vals[j]);
        }
        __syncthreads();
        float* dst = H + ((size_t)side * MODV + r) * MODV;
        for (int i = tid; i < MODV; i += 256) dst[i] = hrow[i];
    }
}

// acc[side][s][o] = sum_cc H[side][s][cc] * Wfft_t[cc][o]
// R0 geometry (320 blocks, latency-hiding TLP restored) + transposed LDS
// (1 ds_read_b128/cc instead of 4 b32) + 8-deep W prefetch for ILP.
__global__ __launch_bounds__(512)
void fft_gemm(const float* __restrict__ H, const float* __restrict__ Wfft_t,
              float* __restrict__ acc) {
    __shared__ float hst[MODV][4];                   // [cc][j], 10 KB
    int o = threadIdx.x;                             // 0..511
    int b = blockIdx.x;
    int side = b / 160;
    int s0   = (b % 160) * 4;
    const float* Hs = H + ((size_t)side * MODV + s0) * MODV;
    for (int t = threadIdx.x; t < 4 * MODV; t += 512) {
        int j = t / MODV, cc = t - j * MODV;
        hst[cc][j] = Hs[t];
    }
    __syncthreads();
    float a0 = 0, a1 = 0, a2 = 0, a3 = 0;
    const float* wp = Wfft_t + o;
    for (int cc0 = 0; cc0 < MODV; cc0 += 8) {
        float w[8];
#pragma unroll
        for (int u = 0; u < 8; u++) w[u] = wp[(size_t)(cc0 + u) * FT_OUT];
#pragma unroll
        for (int u = 0; u < 8; u++) {
            float4 hv = *(const float4*)hst[cc0 + u];
            a0 += hv.x * w[u]; a1 += hv.y * w[u];
            a2 += hv.z * w[u]; a3 += hv.w * w[u];
        }
    }
    float* dst = acc + ((size_t)side * MODV + s0) * FT_OUT + o;
    dst[0] = a0; dst[FT_OUT] = a1;
    dst[2 * FT_OUT] = a2; dst[3 * FT_OUT] = a3;
}

// XCD-sliced gather main. slice = bid%8 (+8 in phase 1): all blocks on XCD x
// gather only from slice x's contiguous 3 MB -> L2-resident (4 MB/XCD).
// Phases are time-separated (bid<32768 does slices 0-7, then 8-15) so each
// XCD's working set is one slice at a time. 4 rows/block, 1 row/wave.
// Lane: q=lane>>4 (k-quarter), fp=lane&15 (feature pair 2fp,2fp+1 in slice).
__global__ __launch_bounds__(256)
void main_slice(const int* __restrict__ stm, const int* __restrict__ nstm,
                const float* __restrict__ vals,
                const unsigned short* __restrict__ Wt,
                const float* __restrict__ b_ft, const float* __restrict__ b_fft,
                const float* __restrict__ fft_acc,
                const float* __restrict__ W_out, float* __restrict__ partial) {
    int bid   = blockIdx.x;
    int phase = bid >> 15;                       // 32768 blocks per phase
    int slice = (bid & 7) + (phase << 3);
    int rowgrp = (bid & 32767) >> 3;
    int tid = threadIdx.x;

    __shared__ int   s_c[4][2][NNZ_PER];
    __shared__ float s_v[4][NNZ_PER];
    {
        int r = tid >> 5, k = tid & 31;
        int row = rowgrp * 4 + (r & 3);
        if (r < 4) {
            s_c[r][0][k] = stm[NNZ + row * NNZ_PER + k];
            s_v[r][k]    = vals[row * NNZ_PER + k];
        } else {
            s_c[r - 4][1][k] = nstm[NNZ + row * NNZ_PER + k];
        }
    }
    __syncthreads();

    int wid  = tid >> 6;
    int lane = tid & 63;
    int row  = rowgrp * 4 + wid;
    int q    = lane >> 4;
    int fp   = lane & 15;

    // uint view: 16 uints (32 bf16) per col within this slice
    const unsigned int* ws = (const unsigned int*)Wt + (size_t)slice * F_BIG * 16 + fp;

    float f0 = 0, f1 = 0, g0 = 0, g1 = 0;
#pragma unroll
    for (int kb = 0; kb < 8; kb++) {
        int kk = kb * 4 + q;
        float v = s_v[wid][kk];
        unsigned int w0 = ws[(size_t)s_c[wid][0][kk] * 16];
        unsigned int w1 = ws[(size_t)s_c[wid][1][kk] * 16];
        float lo, hi;
        unpack_bf16x2(w0, lo, hi); f0 += v * lo; f1 += v * hi;
        unpack_bf16x2(w1, lo, hi); g0 += v * lo; g1 += v * hi;
    }
    // merge the 4 k-quarters (lanes with same fp end identical)
    f0 += __shfl_xor(f0, 16, 64); f0 += __shfl_xor(f0, 32, 64);
    f1 += __shfl_xor(f1, 16, 64); f1 += __shfl_xor(f1, 32, 64);
    g0 += __shfl_xor(g0, 16, 64); g0 += __shfl_xor(g0, 32, 64);
    g1 += __shfl_xor(g1, 16, 64); g1 += __shfl_xor(g1, 32, 64);

    int fo = slice * SL_F + 2 * fp;              // original feature index
    float2 bf  = *(const float2*)(b_ft + fo);
    float2 bb  = *(const float2*)(b_fft + fo);
    float2 wo0 = *(const float2*)(W_out + fo);
    float2 wo1 = *(const float2*)(W_out + FT_OUT + fo);
    float fa0x = 0, fa0y = 0, fa1x = 0, fa1y = 0;
    if (row < MODV) {
        float2 t0 = *(const float2*)(fft_acc + (size_t)row * FT_OUT + fo);
        float2 t1 = *(const float2*)(fft_acc + (size_t)(MODV + row) * FT_OUT + fo);
        fa0x = t0.x; fa0y = t0.y; fa1x = t1.x; fa1y = t1.y;
    }

    float h, dot = 0.0f;
    h = clip01(f0 + bf.x + bb.x + fa0x); dot += h * wo0.x;
    h = clip01(f1 + bf.y + bb.y + fa0y); dot += h * wo0.y;
    h = clip01(g0 + bf.x + bb.x + fa1x); dot += h * wo1.x;
    h = clip01(g1 + bf.y + bb.y + fa1y); dot += h * wo1.y;

    // each fp appears on 4 lanes -> wave sum = 4x the slice dot
#pragma unroll
    for (int off = 32; off > 0; off >>= 1)
        dot += __shfl_down(dot, off, 64);
    if (lane == 0)
        partial[(size_t)slice * B_SZ + row] = dot * 0.25f;
}

__global__ __launch_bounds__(256)
void finish(const float* __restrict__ partial, const float* __restrict__ b_out,
            float* __restrict__ out) {
    int row = blockIdx.x * 256 + threadIdx.x;
    float s = b_out[0];
#pragma unroll
    for (int j = 0; j < NSLICE; j++)
        s += partial[(size_t)j * B_SZ + row];
    out[row] = 1.0f / (1.0f + expf(-s));
}

extern "C" void kernel_launch(void* const* d_in, const int* in_sizes, int n_in,
                              void* d_out, int out_size, void* d_ws, size_t ws_size,
                              hipStream_t stream) {
    const int*   stm   = (const int*)d_in[0];
    const int*   nstm  = (const int*)d_in[1];
    const float* vals  = (const float*)d_in[2];
    // d_in[3]: size scalar (compile-time B_SZ)
    const float* W_ft  = (const float*)d_in[4];
    const float* b_ft  = (const float*)d_in[5];
    const float* W_fft = (const float*)d_in[6];
    const float* b_fft = (const float*)d_in[7];
    const float* W_out = (const float*)d_in[8];
    const float* b_out = (const float*)d_in[9];
    float* out = (float*)d_out;

    unsigned short* Wt_bf = (unsigned short*)d_ws;                  // F_BIG*FT_OUT ushort
    float* Wfft_t  = (float*)(Wt_bf + (size_t)F_BIG * FT_OUT);      // MODV*FT_OUT
    float* H       = Wfft_t + (size_t)MODV * FT_OUT;                // 2*MODV*MODV
    float* fft_acc = H + (size_t)2 * MODV * MODV;                   // 2*MODV*FT_OUT
    float* partial = fft_acc + (size_t)2 * MODV * FT_OUT;           // NSLICE*B_SZ

    // order: small-prep -> fft (fills fft_acc) -> big transpose (Wt lands in
    // L2/L3 warm) -> sliced main -> reduce. No memsets needed: H, partial
    // fully written by their owners.
    prep_small<<<PREPS_GRID, 256, 0, stream>>>(W_fft, stm, nstm, vals, Wfft_t, H);
    fft_gemm<<<320, 512, 0, stream>>>(H, Wfft_t, fft_acc);
    prep_big<<<TP_A, 256, 0, stream>>>(W_ft, Wt_bf);
    main_slice<<<MAIN_GRID, 256, 0, stream>>>(stm, nstm, vals, Wt_bf, b_ft, b_fft,
                                              fft_acc, W_out, partial);
    finish<<<B_SZ / 256, 256, 0, stream>>>(partial, b_out, out);
}